// Round 7
// baseline (478.312 us; speedup 1.0000x reference)
//
#include <hip/hip_runtime.h>

typedef __bf16 bf16_t;
typedef bf16_t bf16x4 __attribute__((ext_vector_type(4)));
typedef bf16_t bf16x8 __attribute__((ext_vector_type(8)));
typedef float f32x4 __attribute__((ext_vector_type(4)));

#define DD 1024
#define TT 4096

__device__ __forceinline__ void gload16(const void* g, void* l) {
    __builtin_amdgcn_global_load_lds(
        (const __attribute__((address_space(1))) void*)g,
        (__attribute__((address_space(3))) void*)l, 16, 0, 0);
}

// ---------------- fp32 -> bf16 convert ----------------
__global__ __launch_bounds__(256) void cvt_bf16_k(const float* __restrict__ s,
                                                  bf16_t* __restrict__ d, int n) {
    int i = (blockIdx.x * 256 + threadIdx.x) * 4;
    if (i < n) {
        const float4 v = *(const float4*)(s + i);
        bf16x4 o;
        o[0] = (bf16_t)v.x; o[1] = (bf16_t)v.y; o[2] = (bf16_t)v.z; o[3] = (bf16_t)v.w;
        *(bf16x4*)(d + i) = o;
    }
}

// ---------------- interleaved convert: dst row 2c = s0 row c, 2c+1 = s1 row c ----------------
__global__ __launch_bounds__(256) void cvt_ileave_k(const float* __restrict__ s0,
                                                    const float* __restrict__ s1,
                                                    bf16_t* __restrict__ d, int total) {
    int i = (blockIdx.x * 256 + threadIdx.x) * 4;
    if (i < total) {
        const int rp = i >> 10, k = i & 1023;
        const int c = rp >> 1;
        const float* src = ((rp & 1) ? s1 : s0) + (long)c * 1024 + k;
        const float4 v = *(const float4*)src;
        bf16x4 o;
        o[0] = (bf16_t)v.x; o[1] = (bf16_t)v.y; o[2] = (bf16_t)v.z; o[3] = (bf16_t)v.w;
        *(bf16x4*)(d + i) = o;
    }
}

// ---------------- rmsnorm (1 block per row, 256 thr x 4 elems), bf16 out ----------------
__global__ __launch_bounds__(256) void rmsnorm_k(const float* __restrict__ x,
                                                 const float* __restrict__ w,
                                                 bf16_t* __restrict__ ob) {
    const long row = blockIdx.x;
    const float* xr = x + row * DD;
    const int t4 = threadIdx.x * 4;
    float4 v = *(const float4*)(xr + t4);
    float s = v.x*v.x + v.y*v.y + v.z*v.z + v.w*v.w;
    #pragma unroll
    for (int off = 1; off < 64; off <<= 1) s += __shfl_xor(s, off);
    __shared__ float red[4];
    if ((threadIdx.x & 63) == 0) red[threadIdx.x >> 6] = s;
    __syncthreads();
    float tot = red[0] + red[1] + red[2] + red[3];
    float sc = rsqrtf(tot * (1.0f / DD) + 1e-6f);
    float4 wv = *(const float4*)(w + t4);
    bf16x4 o;
    o[0] = (bf16_t)(v.x*sc*wv.x); o[1] = (bf16_t)(v.y*sc*wv.y);
    o[2] = (bf16_t)(v.z*sc*wv.z); o[3] = (bf16_t)(v.w*sc*wv.w);
    *(bf16x4*)(ob + row * DD + t4) = o;
}

// ---------------- causal depthwise conv K=4 (bf16 in, bf16 out) ----------------
__global__ __launch_bounds__(256) void conv_k(const bf16_t* __restrict__ h,
                                              const float* __restrict__ cw,
                                              const float* __restrict__ cb,
                                              bf16_t* __restrict__ hc) {
    const long idx = (long)blockIdx.x * 256 + threadIdx.x;  // over B*T*D
    const int d = (int)(idx & (DD - 1));
    const long bt = idx >> 10;
    const int t = (int)(bt & (TT - 1));
    const float w0 = cw[d*4+0], w1 = cw[d*4+1], w2 = cw[d*4+2], w3 = cw[d*4+3];
    const bf16_t* hp = h + bt * DD + d;
    float acc = cb[d] + (float)hp[0] * w3;
    if (t >= 1) acc += (float)hp[-DD]     * w2;
    if (t >= 2) acc += (float)hp[-2*DD]   * w1;
    if (t >= 3) acc += (float)hp[-3*DD]   * w0;
    hc[idx] = (bf16_t)acc;
}

// ---------------- scan pass1: per-chunk summaries only (cd63, i63) ----------------
__global__ __launch_bounds__(256) void scan1_k(const float* __restrict__ ap,
                                               const float* __restrict__ sp,
                                               float* __restrict__ cd63,
                                               float* __restrict__ i63) {
    const int d = blockIdx.x * 256 + threadIdx.x;  // 0..1023
    const int c = blockIdx.y;                      // chunk 0..63
    const int b = blockIdx.z;                      // batch
    const long rowbase = (long)b * TT + (long)c * 64;
    float la = 0.0f, rs = 0.0f, cdv = 0.0f, it = 0.0f;
    for (int t = 0; t < 64; t++) {
        const long off = (rowbase + t) * DD + d;
        const float a = ap[off];
        const float s = sp[off];
        const float sig = sqrtf(fmaxf(1.0f - a * a, 1e-8f)) * s;
        la += __logf(fmaxf(a, 1e-10f));
        cdv = __expf(la);
        rs += sig / fmaxf(cdv, 1e-10f);
        it = cdv * rs;
    }
    const long o = ((long)b * 64 + c) * DD + d;
    cd63[o] = cdv;
    i63[o]  = it;
}

// ---------------- pass2: cross-chunk carry (state ENTERING each chunk) ----------------
__global__ __launch_bounds__(256) void scan2_k(const float* __restrict__ cd63,
                                               const float* __restrict__ i63,
                                               float* __restrict__ carry_in) {
    const int g = blockIdx.x * 256 + threadIdx.x;  // 0..2047
    const int b = g >> 10, d = g & (DD - 1);
    float st = 0.0f;
    for (int c = 0; c < 64; c++) {
        const long o = ((long)b * 64 + c) * DD + d;
        carry_in[o] = st;
        st = i63[o] + cd63[o] * st;
    }
}

// ---------------- pass3: recompute chunk recurrence, fold carry, write bf16 ----------------
__global__ __launch_bounds__(256) void scan3_k(const float* __restrict__ ap,
                                               const float* __restrict__ sp,
                                               const float* __restrict__ carry_in,
                                               bf16_t* __restrict__ rec) {
    const int d = blockIdx.x * 256 + threadIdx.x;
    const int c = blockIdx.y;
    const int b = blockIdx.z;
    const long rowbase = (long)b * TT + (long)c * 64;
    const float carry = carry_in[((long)b * 64 + c) * DD + d];
    float la = 0.0f, rs = 0.0f;
    for (int t = 0; t < 64; t++) {
        const long off = (rowbase + t) * DD + d;
        const float a = ap[off];
        const float s = sp[off];
        const float sig = sqrtf(fmaxf(1.0f - a * a, 1e-8f)) * s;
        la += __logf(fmaxf(a, 1e-10f));
        const float cdv = __expf(la);
        rs += sig / fmaxf(cdv, 1e-10f);
        rec[off] = (bf16_t)(cdv * rs + cdv * carry);
    }
}

// ---------------- bf16 GEMM, C = A(M,K) * B(N,K)^T ----------------
// BM=256, BN=NREP*64, BK=64, 8 waves (2M x 4N).
// m201-faithful 4-phase K-loop: per phase {ds_reads (4-8) -> 2 gload_lds ->
// barrier -> setprio(1) 16(or 8) MFMA setprio(0) -> barrier}. B fragments are
// read once per k-half (ph1/ph2) and HELD IN REGISTERS for ph3/ph4, so the
// B LDS region is dead after ph2. Staging slots (per wave, 2 loads/phase):
//   ph1/ph2: A(t+1) -> other buffer (dead since end of prev tile)
//   ph3/ph4: B(t+2) -> current buffer's dead B region
// One counted vmcnt per K-tile at ph4 (keeps B(t+2) in flight; drains
// A(t+1)+B(t+1)). Reads-before-barrier + per-wave dependency waitcnts give
// LDS-service/MFMA stagger overlap across waves (the m201 mechanism).
// T2 swizzle, T5 setprio, T1 XCD chunk w/ column-major order inside chunk.
enum { EPI_SIGB = 0, EPI_ADDRES = 1, EPI_IV = 2, EPI_GU = 3 };

template<int EPI, int NREP>
__global__ __launch_bounds__(512, 2) void gemm4p_k(const bf16_t* __restrict__ Ag,
                                                   const bf16_t* __restrict__ Bg,
                                                   int M, int N, int K,
                                                   float* outF, bf16_t* outB,
                                                   const float* aux, int ldc) {
    constexpr int BN  = NREP * 64;
    constexpr int ASZ = 16384;        // 256 x 64 bf16
    constexpr int BSZ = BN * 64;
    constexpr int BUF = ASZ + BSZ;
    extern __shared__ bf16_t smem[];  // [2][A | B]
    const int tid = threadIdx.x;
    const int l = tid & 63;
    const int w = tid >> 6;
    const int wm = w >> 2, wn = w & 3;

    // XCD-aware mapping: xcd = lin&7 owns a contiguous chunk; column-major inside.
    const int gx = gridDim.x;
    const int gy = gridDim.y;
    const int lin = blockIdx.y * gx + blockIdx.x;
    long row0, col0;
    if ((gy & 7) == 0) {
        const int rpc = gy >> 3;
        const int q = lin >> 3;
        row0 = (long)((lin & 7) * rpc + q % rpc) * 256;
        col0 = (long)(q / rpc) * (long)BN;
    } else {
        row0 = (long)blockIdx.y * 256;
        col0 = (long)blockIdx.x * BN;
    }

    const int srow = l >> 3;
    const int scol = ((l & 7) ^ srow) * 8;   // pre-swizzled source column
    const long aBase = row0 + srow;
    const long bBase = col0 + srow;
    const int R0a = w * 32;                  // A rows staged by this wave
    const int R0b = w * (BN / 8);            // B rows staged by this wave

    const int NT = K >> 6;
    f32x4 acc[8][NREP] = {};

    // fragment element-offset bases within one buffer (swizzle folded in).
    const int lq2 = (l >> 4) * 16;           // byte k-offset of this lane quarter
    const int rA = wm * 128 + (l & 15);
    const int rB = wn * (NREP * 16) + (l & 15);
    const int eA0 = rA * 64 + ((lq2 ^ ((rA & 7) << 4)) >> 1);
    const int eB0 = ASZ + rB * 64 + ((lq2 ^ ((rB & 7) << 4)) >> 1);

    #define ST_A(tt, off, i)                                                        \
        gload16(Ag + (aBase + R0a + (i) * 8) * (long)K + (long)(tt) * 64 + scol,    \
                &smem[(off) + (R0a + (i) * 8) * 64])
    #define ST_B(tt, off, i)                                                        \
        gload16(Bg + (bBase + R0b + (i) * 8) * (long)K + (long)(tt) * 64 + scol,    \
                &smem[(off) + ASZ + (R0b + (i) * 8) * 64])
    #define BAR asm volatile("s_barrier" ::: "memory")

    // prologue: B(0),A(0) -> buf0; B(1) -> buf1; drain all but B(1).
    #pragma unroll
    for (int i = 0; i < NREP; i++) ST_B(0, 0, i);
    #pragma unroll
    for (int i = 0; i < 4; i++)    ST_A(0, 0, i);
    #pragma unroll
    for (int i = 0; i < NREP; i++) ST_B(1, BUF, i);
    if constexpr (NREP == 4) { asm volatile("s_waitcnt vmcnt(4)" ::: "memory"); }
    else                     { asm volatile("s_waitcnt vmcnt(2)" ::: "memory"); }
    BAR;

    for (int t = 0; t < NT; t++) {
        const int cur = (t & 1) * BUF;
        const int oth = BUF - cur;
        bf16x8 bk0[NREP], bk1[NREP], af[4];

        // ---- ph1: read Bk0 + A[m0-3,k0]; stage A(t+1) 0,1 -> oth; BAR; 16 MFMA; BAR
        #pragma unroll
        for (int n = 0; n < NREP; n++)
            bk0[n] = *(const bf16x8*)&smem[cur + eB0 + n * 1024];
        #pragma unroll
        for (int m = 0; m < 4; m++)
            af[m] = *(const bf16x8*)&smem[cur + eA0 + m * 1024];
        if (t + 1 < NT) { ST_A(t + 1, oth, 0); ST_A(t + 1, oth, 1); }
        BAR;
        __builtin_amdgcn_s_setprio(1);
        #pragma unroll
        for (int m = 0; m < 4; m++)
            #pragma unroll
            for (int n = 0; n < NREP; n++)
                acc[m][n] = __builtin_amdgcn_mfma_f32_16x16x32_bf16(af[m], bk0[n], acc[m][n], 0, 0, 0);
        __builtin_amdgcn_s_setprio(0);
        BAR;

        // ---- ph2: read Bk1 + A[m0-3,k1]; stage A(t+1) 2,3; BAR; 16 MFMA; BAR
        #pragma unroll
        for (int n = 0; n < NREP; n++)
            bk1[n] = *(const bf16x8*)&smem[cur + (eB0 ^ 32) + n * 1024];
        #pragma unroll
        for (int m = 0; m < 4; m++)
            af[m] = *(const bf16x8*)&smem[cur + (eA0 ^ 32) + m * 1024];
        if (t + 1 < NT) { ST_A(t + 1, oth, 2); ST_A(t + 1, oth, 3); }
        BAR;
        __builtin_amdgcn_s_setprio(1);
        #pragma unroll
        for (int m = 0; m < 4; m++)
            #pragma unroll
            for (int n = 0; n < NREP; n++)
                acc[m][n] = __builtin_amdgcn_mfma_f32_16x16x32_bf16(af[m], bk1[n], acc[m][n], 0, 0, 0);
        __builtin_amdgcn_s_setprio(0);
        BAR;

        // ---- ph3: read A[m4-7,k0]; stage B(t+2) 0,1 -> cur's dead B; BAR; 16 MFMA (bk0 regs); BAR
        #pragma unroll
        for (int m = 0; m < 4; m++)
            af[m] = *(const bf16x8*)&smem[cur + eA0 + 4096 + m * 1024];
        if (t + 2 < NT) { ST_B(t + 2, cur, 0); ST_B(t + 2, cur, 1); }
        BAR;
        __builtin_amdgcn_s_setprio(1);
        #pragma unroll
        for (int m = 0; m < 4; m++)
            #pragma unroll
            for (int n = 0; n < NREP; n++)
                acc[m + 4][n] = __builtin_amdgcn_mfma_f32_16x16x32_bf16(af[m], bk0[n], acc[m + 4][n], 0, 0, 0);
        __builtin_amdgcn_s_setprio(0);
        BAR;

        // ---- ph4: read A[m4-7,k1]; stage B(t+2) 2,3 (NREP=4); vmcnt; BAR; 16 MFMA (bk1); BAR
        #pragma unroll
        for (int m = 0; m < 4; m++)
            af[m] = *(const bf16x8*)&smem[cur + (eA0 ^ 32) + 4096 + m * 1024];
        if (t + 2 < NT) {
            if constexpr (NREP == 4) { ST_B(t + 2, cur, 2); ST_B(t + 2, cur, 3); }
            if constexpr (NREP == 4) { asm volatile("s_waitcnt vmcnt(4)" ::: "memory"); }
            else                     { asm volatile("s_waitcnt vmcnt(2)" ::: "memory"); }
        } else {
            asm volatile("s_waitcnt vmcnt(0)" ::: "memory");
        }
        BAR;
        __builtin_amdgcn_s_setprio(1);
        #pragma unroll
        for (int m = 0; m < 4; m++)
            #pragma unroll
            for (int n = 0; n < NREP; n++)
                acc[m + 4][n] = __builtin_amdgcn_mfma_f32_16x16x32_bf16(af[m], bk1[n], acc[m + 4][n], 0, 0, 0);
        __builtin_amdgcn_s_setprio(0);
        BAR;
    }
    #undef ST_A
    #undef ST_B
    #undef BAR

    // ---- epilogue ----
    #pragma unroll
    for (int m = 0; m < 8; m++) {
        const long r0 = row0 + wm * 128 + m * 16 + (l >> 4) * 4;
        #pragma unroll
        for (int n = 0; n < NREP; n++) {
            const long cc = col0 + wn * (NREP * 16) + n * 16 + (l & 15);
            f32x4 v = acc[m][n];
            #pragma unroll
            for (int j = 0; j < 4; j++) {
                const long r = r0 + j;
                const float xv = v[j];
                if (EPI == EPI_SIGB) {
                    outF[r * ldc + cc] = 1.0f / (1.0f + __expf(-(xv + aux[cc])));
                } else if (EPI == EPI_ADDRES) {
                    outF[r * ldc + cc] = xv + aux[r * ldc + cc];
                } else if (EPI == EPI_IV) {
                    const float px = __shfl_xor(xv, 1);
                    if ((l & 1) == 0)
                        outF[r * ldc + (cc >> 1)] = px / (1.0f + __expf(-xv));
                } else {  // EPI_GU
                    const float px = __shfl_xor(xv, 1);
                    if ((l & 1) == 0)
                        outB[r * ldc + (cc >> 1)] = (bf16_t)(xv / (1.0f + __expf(-xv)) * px);
                }
            }
        }
    }
}

extern "C" void kernel_launch(void* const* d_in, const int* in_sizes, int n_in,
                              void* d_out, int out_size, void* d_ws, size_t ws_size,
                              hipStream_t stream) {
    const float* x   = (const float*)d_in[0];
    const float* pnw = (const float*)d_in[1];
    const float* cw  = (const float*)d_in[2];
    const float* cb  = (const float*)d_in[3];
    const float* wa  = (const float*)d_in[4];
    const float* wi  = (const float*)d_in[5];
    const float* wv  = (const float*)d_in[6];
    const float* wop = (const float*)d_in[7];
    const float* db  = (const float*)d_in[8];
    const float* fnw = (const float*)d_in[9];
    const float* wgu = (const float*)d_in[10];
    const float* wdn = (const float*)d_in[11];
    float* out = (float*)d_out;

    // ---- workspace layout (total ~129.5 MiB) ----
    char* ws = (char*)d_ws;
    bf16_t* wab   = (bf16_t*)(ws + 0);            // 1024x1024 bf16
    bf16_t* wivb  = (bf16_t*)(ws + 2097152);      // 2048x1024 bf16 (i|v interleaved)
    bf16_t* wopb  = (bf16_t*)(ws + 6291456);      // 1024x1024 bf16
    bf16_t* wgub  = (bf16_t*)(ws + 8388608);      // 8192x1024 bf16 (gate|up interleaved)
    bf16_t* wdnb  = (bf16_t*)(ws + 25165824);     // 4096x1024 bf16
    bf16_t* hb    = (bf16_t*)(ws + 33554432);     // 8192x1024 bf16 (reused: hn)
    bf16_t* hn    = hb;
    bf16_t* hc    = (bf16_t*)(ws + 50331648);     // 8192x1024 bf16 (reused: rec)
    bf16_t* rec   = hc;
    float*  a_p   = (float*)(ws + 67108864);      // 8192x1024 f32 (reused by act)
    float*  s_p   = (float*)(ws + 100663296);     // 8192x1024 f32
    bf16_t* act   = (bf16_t*)(ws + 67108864);     // 8192x4096 bf16 (after scan)
    float*  cd63  = (float*)(ws + 134217728);
    float*  i63   = (float*)(ws + 134742016);
    float*  carry = (float*)(ws + 135266304);

    const int LDS4 = 131072;   // NREP=4
    const int LDS2 = 98304;    // NREP=2
    hipFuncSetAttribute((const void*)gemm4p_k<EPI_SIGB, 2>,   hipFuncAttributeMaxDynamicSharedMemorySize, LDS2);
    hipFuncSetAttribute((const void*)gemm4p_k<EPI_IV, 4>,     hipFuncAttributeMaxDynamicSharedMemorySize, LDS4);
    hipFuncSetAttribute((const void*)gemm4p_k<EPI_ADDRES, 2>, hipFuncAttributeMaxDynamicSharedMemorySize, LDS2);
    hipFuncSetAttribute((const void*)gemm4p_k<EPI_GU, 4>,     hipFuncAttributeMaxDynamicSharedMemorySize, LDS4);

    // weight converts / interleaves
    cvt_bf16_k  <<<1024, 256, 0, stream>>>(wa,  wab,  1048576);
    cvt_ileave_k<<<2048, 256, 0, stream>>>(wi,  wv, wivb, 2097152);
    cvt_bf16_k  <<<1024, 256, 0, stream>>>(wop, wopb, 1048576);
    cvt_ileave_k<<<8192, 256, 0, stream>>>(wgu, wgu + 4194304, wgub, 8388608);
    cvt_bf16_k  <<<4096, 256, 0, stream>>>(wdn, wdnb, 4194304);

    // pre-norm + conv
    rmsnorm_k<<<8192, 256, 0, stream>>>(x, pnw, hb);
    conv_k<<<32768, 256, 0, stream>>>(hb, cw, cb, hc);

    // a-plane: sigmoid(h*w_a^T + db);  s-plane: sigmoid(h*w_i^T) * (h*w_v^T)
    gemm4p_k<EPI_SIGB, 2><<<dim3(8, 32), 512, LDS2, stream>>>(hc, wab,  8192, 1024, 1024,
                                                              a_p, nullptr, db, 1024);
    gemm4p_k<EPI_IV, 4>  <<<dim3(8, 32), 512, LDS4, stream>>>(hc, wivb, 8192, 2048, 1024,
                                                              s_p, nullptr, nullptr, 1024);
    // chunked scan (matches reference's clipped formula); pass3 recomputes
    scan1_k<<<dim3(4, 64, 2), 256, 0, stream>>>(a_p, s_p, cd63, i63);
    scan2_k<<<8, 256, 0, stream>>>(cd63, i63, carry);
    scan3_k<<<dim3(4, 64, 2), 256, 0, stream>>>(a_p, s_p, carry, rec);

    // out_proj + residual -> d_out holds x2
    gemm4p_k<EPI_ADDRES, 2><<<dim3(8, 32), 512, LDS2, stream>>>(rec, wopb, 8192, 1024, 1024,
                                                                out, nullptr, x, 1024);
    // ffn
    rmsnorm_k<<<8192, 256, 0, stream>>>(out, fnw, hn);
    gemm4p_k<EPI_GU, 4><<<dim3(32, 32), 512, LDS4, stream>>>(hn, wgub, 8192, 8192, 1024,
                                                             nullptr, act, nullptr, 4096);
    // down-proj + residual, in place on d_out
    gemm4p_k<EPI_ADDRES, 2><<<dim3(8, 32), 512, LDS2, stream>>>(act, wdnb, 8192, 1024, 4096,
                                                                out, nullptr, out, 1024);
}